// Round 1
// baseline (1065.961 us; speedup 1.0000x reference)
//
#include <hip/hip_runtime.h>
#include <math.h>

// Problem constants
#define BB 2
#define LL 1024
#define HH 1024
#define NH 16
#define DD 64
#define KK 4
#define HD (NH * DD)   // 1024
#define MM (BB * LL)   // 2048

// ---------------------------------------------------------------------------
// Generic tiled fp32 GEMM: C[M,N] = A[M,K] @ W[N,K]^T + bias, optional act.
// act: 0 = none, 1 = sigmoid, 2 = softplus
// 64x64 tile, 256 threads, 4x4 microtile/thread, BK=16.
// ---------------------------------------------------------------------------
__global__ __launch_bounds__(256) void gemm_bias_act(
    const float* __restrict__ A, const float* __restrict__ W,
    const float* __restrict__ bias, float* __restrict__ C,
    int M, int N, int Kd, int act)
{
    __shared__ float As[16][68];
    __shared__ float Bs[16][68];
    const int tid = threadIdx.x;
    const int bm = blockIdx.y * 64;
    const int bn = blockIdx.x * 64;
    const int tx = tid & 15;        // 0..15 (col group)
    const int ty = tid >> 4;        // 0..15 (row group)
    const int lr = tid >> 2;        // 0..63 load row
    const int lk = (tid & 3) << 2;  // 0,4,8,12 load k offset

    float acc[4][4] = {};

    for (int k0 = 0; k0 < Kd; k0 += 16) {
        float4 av = *(const float4*)(A + (size_t)(bm + lr) * Kd + k0 + lk);
        float4 wv = make_float4(0.f, 0.f, 0.f, 0.f);
        if (bn + lr < N)
            wv = *(const float4*)(W + (size_t)(bn + lr) * Kd + k0 + lk);
        __syncthreads();
        As[lk + 0][lr] = av.x; As[lk + 1][lr] = av.y;
        As[lk + 2][lr] = av.z; As[lk + 3][lr] = av.w;
        Bs[lk + 0][lr] = wv.x; Bs[lk + 1][lr] = wv.y;
        Bs[lk + 2][lr] = wv.z; Bs[lk + 3][lr] = wv.w;
        __syncthreads();
        #pragma unroll
        for (int kk = 0; kk < 16; ++kk) {
            float4 a = *(const float4*)&As[kk][ty * 4];
            float4 b = *(const float4*)&Bs[kk][tx * 4];
            acc[0][0] = fmaf(a.x, b.x, acc[0][0]);
            acc[0][1] = fmaf(a.x, b.y, acc[0][1]);
            acc[0][2] = fmaf(a.x, b.z, acc[0][2]);
            acc[0][3] = fmaf(a.x, b.w, acc[0][3]);
            acc[1][0] = fmaf(a.y, b.x, acc[1][0]);
            acc[1][1] = fmaf(a.y, b.y, acc[1][1]);
            acc[1][2] = fmaf(a.y, b.z, acc[1][2]);
            acc[1][3] = fmaf(a.y, b.w, acc[1][3]);
            acc[2][0] = fmaf(a.z, b.x, acc[2][0]);
            acc[2][1] = fmaf(a.z, b.y, acc[2][1]);
            acc[2][2] = fmaf(a.z, b.z, acc[2][2]);
            acc[2][3] = fmaf(a.z, b.w, acc[2][3]);
            acc[3][0] = fmaf(a.w, b.x, acc[3][0]);
            acc[3][1] = fmaf(a.w, b.y, acc[3][1]);
            acc[3][2] = fmaf(a.w, b.z, acc[3][2]);
            acc[3][3] = fmaf(a.w, b.w, acc[3][3]);
        }
    }

    #pragma unroll
    for (int i = 0; i < 4; ++i) {
        int row = bm + ty * 4 + i;
        #pragma unroll
        for (int j = 0; j < 4; ++j) {
            int col = bn + tx * 4 + j;
            if (col < N) {
                float val = acc[i][j] + (bias ? bias[col] : 0.f);
                if (act == 1) {
                    val = 1.f / (1.f + expf(-val));
                } else if (act == 2) {
                    val = fmaxf(val, 0.f) + log1pf(expf(-fabsf(val)));
                }
                C[(size_t)row * N + col] = val;
            }
        }
    }
}

// ---------------------------------------------------------------------------
// Gated delta recurrence. One block per (b, h) chain: 32 blocks, 256 threads.
// Lane layout: row r = tid>>2 (0..63), e-chunk h4 = tid&3 (16 e-values each).
// State S[r][e] kept in registers (16 floats / lane).
// S_new[d,e] = alpha*S[d,e] + (beta*v[d] - alpha*beta*(S k)[d]) * k[e]
// o[d] = sum_e S_new[d,e] * q[e]
// ---------------------------------------------------------------------------
__global__ __launch_bounds__(256) void gdn_recurrence(
    const float* __restrict__ q, const float* __restrict__ k,
    const float* __restrict__ v, const float* __restrict__ alpha,
    const float* __restrict__ beta, float* __restrict__ att)
{
    const int bh = blockIdx.x;
    const int b = bh >> 4;
    const int h = bh & 15;
    const int tid = threadIdx.x;
    const int r = tid >> 2;
    const int e4 = (tid & 3) * 16;

    const size_t base = ((size_t)b * LL * NH + h) * DD;
    const float* qp = q + base + e4;
    const float* kp = k + base + e4;
    const float* vp = v + base + r;
    const float* ap = alpha + (size_t)b * LL * NH + h;
    const float* bp = beta + (size_t)b * LL * NH + h;
    float* op = att + ((size_t)(b * NH + h) * LL) * DD + r;

    float S[16];
    #pragma unroll
    for (int j = 0; j < 16; ++j) S[j] = 0.f;

    alignas(16) float kcur[16], qcur[16], knxt[16], qnxt[16];
    float vcur, acur, bcur, vnxt, anxt, bnxt;

    // prefetch t = 0
    {
        size_t off = 0;
        *(float4*)(kcur + 0)  = *(const float4*)(kp + off + 0);
        *(float4*)(kcur + 4)  = *(const float4*)(kp + off + 4);
        *(float4*)(kcur + 8)  = *(const float4*)(kp + off + 8);
        *(float4*)(kcur + 12) = *(const float4*)(kp + off + 12);
        *(float4*)(qcur + 0)  = *(const float4*)(qp + off + 0);
        *(float4*)(qcur + 4)  = *(const float4*)(qp + off + 4);
        *(float4*)(qcur + 8)  = *(const float4*)(qp + off + 8);
        *(float4*)(qcur + 12) = *(const float4*)(qp + off + 12);
        vcur = vp[off];
        acur = ap[0];
        bcur = bp[0];
    }

    for (int t = 0; t < LL; ++t) {
        // software-pipelined prefetch of t+1 (clamped)
        {
            int tn = (t + 1 < LL) ? (t + 1) : t;
            size_t off = (size_t)tn * (NH * DD);
            *(float4*)(knxt + 0)  = *(const float4*)(kp + off + 0);
            *(float4*)(knxt + 4)  = *(const float4*)(kp + off + 4);
            *(float4*)(knxt + 8)  = *(const float4*)(kp + off + 8);
            *(float4*)(knxt + 12) = *(const float4*)(kp + off + 12);
            *(float4*)(qnxt + 0)  = *(const float4*)(qp + off + 0);
            *(float4*)(qnxt + 4)  = *(const float4*)(qp + off + 4);
            *(float4*)(qnxt + 8)  = *(const float4*)(qp + off + 8);
            *(float4*)(qnxt + 12) = *(const float4*)(qp + off + 12);
            vnxt = vp[off];
            anxt = ap[(size_t)tn * NH];
            bnxt = bp[(size_t)tn * NH];
        }

        // S . k  (per-row dot, 4 accumulators to break the chain)
        float s0 = 0.f, s1 = 0.f, s2 = 0.f, s3 = 0.f;
        #pragma unroll
        for (int j = 0; j < 4; ++j) {
            s0 = fmaf(S[4 * j + 0], kcur[4 * j + 0], s0);
            s1 = fmaf(S[4 * j + 1], kcur[4 * j + 1], s1);
            s2 = fmaf(S[4 * j + 2], kcur[4 * j + 2], s2);
            s3 = fmaf(S[4 * j + 3], kcur[4 * j + 3], s3);
        }
        float sk = (s0 + s1) + (s2 + s3);
        sk += __shfl_xor(sk, 1, 4);
        sk += __shfl_xor(sk, 2, 4);

        float cf = bcur * fmaf(-acur, sk, vcur);

        float o0 = 0.f, o1 = 0.f;
        #pragma unroll
        for (int j = 0; j < 8; ++j) {
            S[2 * j + 0] = fmaf(acur, S[2 * j + 0], cf * kcur[2 * j + 0]);
            S[2 * j + 1] = fmaf(acur, S[2 * j + 1], cf * kcur[2 * j + 1]);
            o0 = fmaf(S[2 * j + 0], qcur[2 * j + 0], o0);
            o1 = fmaf(S[2 * j + 1], qcur[2 * j + 1], o1);
        }
        float o = o0 + o1;
        o += __shfl_xor(o, 1, 4);
        o += __shfl_xor(o, 2, 4);
        if ((tid & 3) == 0) op[(size_t)t * DD] = o;

        #pragma unroll
        for (int j = 0; j < 16; ++j) { kcur[j] = knxt[j]; qcur[j] = qnxt[j]; }
        vcur = vnxt; acur = anxt; bcur = bnxt;
    }
}

// ---------------------------------------------------------------------------
// Residual depthwise causal conv on the bug-compatible reshaped view.
// y viewed as [B, 1024(i), 1024(c)] flat (== [B,NH,L,D] memory).
// x2[b][i][c] = y[b][i][c] + sum_{j=0..3} Wc[c*4+j] * y[b][i-3+j][c]
// ---------------------------------------------------------------------------
__global__ __launch_bounds__(256) void conv_residual(
    const float* __restrict__ y, const float* __restrict__ Wc,
    float* __restrict__ x2)
{
    const int c = blockIdx.x * 256 + threadIdx.x;   // 0..1023
    const int i = blockIdx.y;                        // 0..1023
    const int b = blockIdx.z;                        // 0..1
    const size_t rowbase = ((size_t)b * 1024 + i) * 1024;

    float w0 = Wc[c * 4 + 0], w1 = Wc[c * 4 + 1];
    float w2 = Wc[c * 4 + 2], w3 = Wc[c * 4 + 3];

    float ycur = y[rowbase + c];
    float acc = ycur + w3 * ycur;  // residual + j=3 tap (i-3+3 = i)
    if (i >= 1) acc = fmaf(w2, y[rowbase - 1024 + c], acc);
    if (i >= 2) acc = fmaf(w1, y[rowbase - 2048 + c], acc);
    if (i >= 3) acc = fmaf(w0, y[rowbase - 3072 + c], acc);
    x2[rowbase + c] = acc;
}

// ---------------------------------------------------------------------------
extern "C" void kernel_launch(void* const* d_in, const int* in_sizes, int n_in,
                              void* d_out, int out_size, void* d_ws, size_t ws_size,
                              hipStream_t stream)
{
    const float* hs    = (const float*)d_in[0];
    const float* Wq    = (const float*)d_in[1];
    const float* bq    = (const float*)d_in[2];
    const float* Wk    = (const float*)d_in[3];
    const float* bk    = (const float*)d_in[4];
    const float* Wv    = (const float*)d_in[5];
    const float* bv    = (const float*)d_in[6];
    const float* Wa    = (const float*)d_in[7];
    const float* Wb    = (const float*)d_in[8];
    const float* Wconv = (const float*)d_in[9];
    const float* Wo    = (const float*)d_in[10];
    const float* bo    = (const float*)d_in[11];
    float* out = (float*)d_out;

    float* ws = (float*)d_ws;
    const size_t PROJ = (size_t)MM * HD;   // 2048*1024
    float* qw  = ws;
    float* kw  = qw + PROJ;
    float* vw  = kw + PROJ;
    float* att = vw + PROJ;
    float* x2  = att + PROJ;
    float* al  = x2 + PROJ;
    float* be  = al + (size_t)MM * NH;

    dim3 blk(256);
    dim3 gfull(HD / 64, MM / 64);   // (16, 32)
    dim3 gsmall(1, MM / 64);        // (1, 32)

    // Projections
    hipLaunchKernelGGL(gemm_bias_act, gfull, blk, 0, stream, hs, Wq, bq, qw, MM, HD, HH, 0);
    hipLaunchKernelGGL(gemm_bias_act, gfull, blk, 0, stream, hs, Wk, bk, kw, MM, HD, HH, 0);
    hipLaunchKernelGGL(gemm_bias_act, gfull, blk, 0, stream, hs, Wv, bv, vw, MM, HD, HH, 0);
    hipLaunchKernelGGL(gemm_bias_act, gsmall, blk, 0, stream, hs, Wa, (const float*)nullptr, al, MM, NH, HH, 1);
    hipLaunchKernelGGL(gemm_bias_act, gsmall, blk, 0, stream, hs, Wb, (const float*)nullptr, be, MM, NH, HH, 2);

    // Sequential gated delta recurrence: 32 chains
    hipLaunchKernelGGL(gdn_recurrence, dim3(BB * NH), blk, 0, stream, qw, kw, vw, al, be, att);

    // Residual depthwise causal conv on reshaped view
    hipLaunchKernelGGL(conv_residual, dim3(HD / 256, 1024, BB), blk, 0, stream, att, Wconv, x2);

    // Output projection
    hipLaunchKernelGGL(gemm_bias_act, gfull, blk, 0, stream, x2, Wo, bo, out, MM, HH, HD, 0);
}

// Round 2
// 742.305 us; speedup vs baseline: 1.4360x; 1.4360x over previous
//
#include <hip/hip_runtime.h>
#include <math.h>

// Problem constants
#define BB 2
#define LL 1024
#define HH 1024
#define NH 16
#define DD 64
#define KK 4
#define HD (NH * DD)   // 1024
#define MM (BB * LL)   // 2048
#define CT 32          // recurrence chunk length staged in LDS

// ---------------------------------------------------------------------------
// Generic tiled fp32 GEMM: C[M,N] = A[M,K] @ W[N,K]^T + bias, optional act.
// act: 0 = none, 1 = sigmoid, 2 = softplus
// 64x64 tile, 256 threads, 4x4 microtile/thread, BK=16.
// ---------------------------------------------------------------------------
__global__ __launch_bounds__(256) void gemm_bias_act(
    const float* __restrict__ A, const float* __restrict__ W,
    const float* __restrict__ bias, float* __restrict__ C,
    int M, int N, int Kd, int act)
{
    __shared__ float As[16][68];
    __shared__ float Bs[16][68];
    const int tid = threadIdx.x;
    const int bm = blockIdx.y * 64;
    const int bn = blockIdx.x * 64;
    const int tx = tid & 15;        // 0..15 (col group)
    const int ty = tid >> 4;        // 0..15 (row group)
    const int lr = tid >> 2;        // 0..63 load row
    const int lk = (tid & 3) << 2;  // 0,4,8,12 load k offset

    float acc[4][4] = {};

    for (int k0 = 0; k0 < Kd; k0 += 16) {
        float4 av = *(const float4*)(A + (size_t)(bm + lr) * Kd + k0 + lk);
        float4 wv = make_float4(0.f, 0.f, 0.f, 0.f);
        if (bn + lr < N)
            wv = *(const float4*)(W + (size_t)(bn + lr) * Kd + k0 + lk);
        __syncthreads();
        As[lk + 0][lr] = av.x; As[lk + 1][lr] = av.y;
        As[lk + 2][lr] = av.z; As[lk + 3][lr] = av.w;
        Bs[lk + 0][lr] = wv.x; Bs[lk + 1][lr] = wv.y;
        Bs[lk + 2][lr] = wv.z; Bs[lk + 3][lr] = wv.w;
        __syncthreads();
        #pragma unroll
        for (int kk = 0; kk < 16; ++kk) {
            float4 a = *(const float4*)&As[kk][ty * 4];
            float4 b = *(const float4*)&Bs[kk][tx * 4];
            acc[0][0] = fmaf(a.x, b.x, acc[0][0]);
            acc[0][1] = fmaf(a.x, b.y, acc[0][1]);
            acc[0][2] = fmaf(a.x, b.z, acc[0][2]);
            acc[0][3] = fmaf(a.x, b.w, acc[0][3]);
            acc[1][0] = fmaf(a.y, b.x, acc[1][0]);
            acc[1][1] = fmaf(a.y, b.y, acc[1][1]);
            acc[1][2] = fmaf(a.y, b.z, acc[1][2]);
            acc[1][3] = fmaf(a.y, b.w, acc[1][3]);
            acc[2][0] = fmaf(a.z, b.x, acc[2][0]);
            acc[2][1] = fmaf(a.z, b.y, acc[2][1]);
            acc[2][2] = fmaf(a.z, b.z, acc[2][2]);
            acc[2][3] = fmaf(a.z, b.w, acc[2][3]);
            acc[3][0] = fmaf(a.w, b.x, acc[3][0]);
            acc[3][1] = fmaf(a.w, b.y, acc[3][1]);
            acc[3][2] = fmaf(a.w, b.z, acc[3][2]);
            acc[3][3] = fmaf(a.w, b.w, acc[3][3]);
        }
    }

    #pragma unroll
    for (int i = 0; i < 4; ++i) {
        int row = bm + ty * 4 + i;
        #pragma unroll
        for (int j = 0; j < 4; ++j) {
            int col = bn + tx * 4 + j;
            if (col < N) {
                float val = acc[i][j] + (bias ? bias[col] : 0.f);
                if (act == 1) {
                    val = 1.f / (1.f + expf(-val));
                } else if (act == 2) {
                    val = fmaxf(val, 0.f) + log1pf(expf(-fabsf(val)));
                }
                C[(size_t)row * N + col] = val;
            }
        }
    }
}

// ---------------------------------------------------------------------------
// DPP quad reductions: xor within quads (lanes 0-3, 4-7, ...). 1-cycle VALU
// cross-lane instead of ds_swizzle-based __shfl_xor.
// quad_perm ctrl: [1,0,3,2] = 0xB1 (xor1), [2,3,0,1] = 0x4E (xor2)
// ---------------------------------------------------------------------------
__device__ __forceinline__ float quad_xor1(float x) {
    int i = __builtin_amdgcn_update_dpp(0, __builtin_bit_cast(int, x),
                                        0xB1, 0xF, 0xF, true);
    return __builtin_bit_cast(float, i);
}
__device__ __forceinline__ float quad_xor2(float x) {
    int i = __builtin_amdgcn_update_dpp(0, __builtin_bit_cast(int, x),
                                        0x4E, 0xF, 0xF, true);
    return __builtin_bit_cast(float, i);
}

// ---------------------------------------------------------------------------
// Gated delta recurrence. One block per (b, h) chain: 32 blocks, 256 threads.
// Lane layout: row r = tid>>2 (0..63), e-chunk g = tid&3 (16 e-values each).
// State S[r][e] kept in registers (16 floats / lane).
// q/k/v/alpha/beta staged through LDS in CT-step chunks, double buffered:
// global loads for chunk c+1 issue at top of chunk c's compute (~6K cyc of
// cover), so HBM/L2 latency is paid once per chunk, not per step.
// ---------------------------------------------------------------------------
__global__ __launch_bounds__(256) void gdn_recurrence(
    const float* __restrict__ q, const float* __restrict__ k,
    const float* __restrict__ v, const float* __restrict__ alpha,
    const float* __restrict__ beta, float* __restrict__ att)
{
    __shared__ float ks[2][CT][64];
    __shared__ float qs[2][CT][64];
    __shared__ float vs[2][CT][64];
    __shared__ float as_[2][CT];
    __shared__ float bs_[2][CT];

    const int bh = blockIdx.x;
    const int b = bh >> 4;
    const int h = bh & 15;
    const int tid = threadIdx.x;
    const int r = tid >> 2;         // state row 0..63
    const int g = tid & 3;          // e-slice group
    const int e0 = g * 16;

    const size_t stepstride = (size_t)NH * DD;   // 1024 floats per t
    const float* kbase = k + ((size_t)b * LL * NH + h) * DD;
    const float* qbase = q + ((size_t)b * LL * NH + h) * DD;
    const float* vbase = v + ((size_t)b * LL * NH + h) * DD;
    const float* ap = alpha + (size_t)b * LL * NH + h;
    const float* bp = beta + (size_t)b * LL * NH + h;
    float* op = att + ((size_t)(b * NH + h) * LL) * DD + r;

    // staging indices: 512 float4 per (array, chunk); 2 per thread
    const int fi0 = tid;            // 0..255
    const int fi1 = tid + 256;      // 256..511
    const int t_a = fi0 >> 4, d_a = (fi0 & 15) * 4;
    const int t_b = fi1 >> 4, d_b = (fi1 & 15) * 4;

    float S[16];
    #pragma unroll
    for (int j = 0; j < 16; ++j) S[j] = 0.f;

    // ---- stage chunk 0 into buffer 0 ----
    {
        float4 ka = *(const float4*)(kbase + (size_t)t_a * stepstride + d_a);
        float4 kb = *(const float4*)(kbase + (size_t)t_b * stepstride + d_b);
        float4 qa = *(const float4*)(qbase + (size_t)t_a * stepstride + d_a);
        float4 qb = *(const float4*)(qbase + (size_t)t_b * stepstride + d_b);
        float4 va = *(const float4*)(vbase + (size_t)t_a * stepstride + d_a);
        float4 vb = *(const float4*)(vbase + (size_t)t_b * stepstride + d_b);
        float ab = 0.f;
        if (tid < CT)            ab = ap[(size_t)tid * NH];
        else if (tid < 2 * CT)   ab = bp[(size_t)(tid - CT) * NH];
        *(float4*)&ks[0][t_a][d_a] = ka;  *(float4*)&ks[0][t_b][d_b] = kb;
        *(float4*)&qs[0][t_a][d_a] = qa;  *(float4*)&qs[0][t_b][d_b] = qb;
        *(float4*)&vs[0][t_a][d_a] = va;  *(float4*)&vs[0][t_b][d_b] = vb;
        if (tid < CT)            as_[0][tid] = ab;
        else if (tid < 2 * CT)   bs_[0][tid - CT] = ab;
    }
    __syncthreads();

    const int NCHUNK = LL / CT;
    for (int c = 0; c < NCHUNK; ++c) {
        const int cur = c & 1, nxt = cur ^ 1;

        // ---- issue global loads for chunk c+1 (latency covered by compute) ----
        float4 ka, kb, qa, qb, va, vb;
        float ab = 0.f;
        const bool more = (c + 1 < NCHUNK);
        if (more) {
            const size_t t0n = (size_t)(c + 1) * CT;
            ka = *(const float4*)(kbase + (t0n + t_a) * stepstride + d_a);
            kb = *(const float4*)(kbase + (t0n + t_b) * stepstride + d_b);
            qa = *(const float4*)(qbase + (t0n + t_a) * stepstride + d_a);
            qb = *(const float4*)(qbase + (t0n + t_b) * stepstride + d_b);
            va = *(const float4*)(vbase + (t0n + t_a) * stepstride + d_a);
            vb = *(const float4*)(vbase + (t0n + t_b) * stepstride + d_b);
            if (tid < CT)            ab = ap[(t0n + tid) * NH];
            else if (tid < 2 * CT)   ab = bp[(t0n + tid - CT) * NH];
        }

        // ---- compute CT steps from LDS buffer `cur`, 1-step LDS prefetch ----
        alignas(16) float kcur[16], qcur[16], knxt[16], qnxt[16];
        float vcur, acur, bcur, vnxt, anxt, bnxt;
        #pragma unroll
        for (int j = 0; j < 4; ++j) {
            *(float4*)(kcur + 4 * j) = *(const float4*)&ks[cur][0][e0 + 4 * j];
            *(float4*)(qcur + 4 * j) = *(const float4*)&qs[cur][0][e0 + 4 * j];
        }
        vcur = vs[cur][0][r]; acur = as_[cur][0]; bcur = bs_[cur][0];

        #pragma unroll 2
        for (int t = 0; t < CT; ++t) {
            const int tn = (t + 1 < CT) ? t + 1 : t;
            #pragma unroll
            for (int j = 0; j < 4; ++j) {
                *(float4*)(knxt + 4 * j) = *(const float4*)&ks[cur][tn][e0 + 4 * j];
                *(float4*)(qnxt + 4 * j) = *(const float4*)&qs[cur][tn][e0 + 4 * j];
            }
            vnxt = vs[cur][tn][r]; anxt = as_[cur][tn]; bnxt = bs_[cur][tn];

            // sk = (S . k) over this row (4 accumulators), then quad-reduce
            float s0 = 0.f, s1 = 0.f, s2 = 0.f, s3 = 0.f;
            #pragma unroll
            for (int j = 0; j < 4; ++j) {
                s0 = fmaf(S[4 * j + 0], kcur[4 * j + 0], s0);
                s1 = fmaf(S[4 * j + 1], kcur[4 * j + 1], s1);
                s2 = fmaf(S[4 * j + 2], kcur[4 * j + 2], s2);
                s3 = fmaf(S[4 * j + 3], kcur[4 * j + 3], s3);
            }
            float sk = (s0 + s1) + (s2 + s3);
            sk += quad_xor1(sk);
            sk += quad_xor2(sk);

            const float cf = bcur * fmaf(-acur, sk, vcur);

            // S update + o dot (4 accumulators to shorten the chain)
            float o0 = 0.f, o1 = 0.f, o2 = 0.f, o3 = 0.f;
            #pragma unroll
            for (int j = 0; j < 4; ++j) {
                S[4 * j + 0] = fmaf(acur, S[4 * j + 0], cf * kcur[4 * j + 0]);
                S[4 * j + 1] = fmaf(acur, S[4 * j + 1], cf * kcur[4 * j + 1]);
                S[4 * j + 2] = fmaf(acur, S[4 * j + 2], cf * kcur[4 * j + 2]);
                S[4 * j + 3] = fmaf(acur, S[4 * j + 3], cf * kcur[4 * j + 3]);
                o0 = fmaf(S[4 * j + 0], qcur[4 * j + 0], o0);
                o1 = fmaf(S[4 * j + 1], qcur[4 * j + 1], o1);
                o2 = fmaf(S[4 * j + 2], qcur[4 * j + 2], o2);
                o3 = fmaf(S[4 * j + 3], qcur[4 * j + 3], o3);
            }
            float o = (o0 + o1) + (o2 + o3);
            o += quad_xor1(o);
            o += quad_xor2(o);
            if (g == 0) op[(size_t)(c * CT + t) * DD] = o;

            #pragma unroll
            for (int j = 0; j < 16; ++j) { kcur[j] = knxt[j]; qcur[j] = qnxt[j]; }
            vcur = vnxt; acur = anxt; bcur = bnxt;
        }

        // ---- write staged chunk c+1 into the other buffer, then sync ----
        if (more) {
            *(float4*)&ks[nxt][t_a][d_a] = ka;  *(float4*)&ks[nxt][t_b][d_b] = kb;
            *(float4*)&qs[nxt][t_a][d_a] = qa;  *(float4*)&qs[nxt][t_b][d_b] = qb;
            *(float4*)&vs[nxt][t_a][d_a] = va;  *(float4*)&vs[nxt][t_b][d_b] = vb;
            if (tid < CT)            as_[nxt][tid] = ab;
            else if (tid < 2 * CT)   bs_[nxt][tid - CT] = ab;
        }
        __syncthreads();
    }
}

// ---------------------------------------------------------------------------
// Residual depthwise causal conv on the bug-compatible reshaped view.
// y viewed as [B, 1024(i), 1024(c)] flat (== [B,NH,L,D] memory).
// ---------------------------------------------------------------------------
__global__ __launch_bounds__(256) void conv_residual(
    const float* __restrict__ y, const float* __restrict__ Wc,
    float* __restrict__ x2)
{
    const int c = blockIdx.x * 256 + threadIdx.x;   // 0..1023
    const int i = blockIdx.y;                        // 0..1023
    const int b = blockIdx.z;                        // 0..1
    const size_t rowbase = ((size_t)b * 1024 + i) * 1024;

    float w0 = Wc[c * 4 + 0], w1 = Wc[c * 4 + 1];
    float w2 = Wc[c * 4 + 2], w3 = Wc[c * 4 + 3];

    float ycur = y[rowbase + c];
    float acc = ycur + w3 * ycur;  // residual + j=3 tap
    if (i >= 1) acc = fmaf(w2, y[rowbase - 1024 + c], acc);
    if (i >= 2) acc = fmaf(w1, y[rowbase - 2048 + c], acc);
    if (i >= 3) acc = fmaf(w0, y[rowbase - 3072 + c], acc);
    x2[rowbase + c] = acc;
}

// ---------------------------------------------------------------------------
extern "C" void kernel_launch(void* const* d_in, const int* in_sizes, int n_in,
                              void* d_out, int out_size, void* d_ws, size_t ws_size,
                              hipStream_t stream)
{
    const float* hs    = (const float*)d_in[0];
    const float* Wq    = (const float*)d_in[1];
    const float* bq    = (const float*)d_in[2];
    const float* Wk    = (const float*)d_in[3];
    const float* bk    = (const float*)d_in[4];
    const float* Wv    = (const float*)d_in[5];
    const float* bv    = (const float*)d_in[6];
    const float* Wa    = (const float*)d_in[7];
    const float* Wb    = (const float*)d_in[8];
    const float* Wconv = (const float*)d_in[9];
    const float* Wo    = (const float*)d_in[10];
    const float* bo    = (const float*)d_in[11];
    float* out = (float*)d_out;

    float* ws = (float*)d_ws;
    const size_t PROJ = (size_t)MM * HD;   // 2048*1024
    float* qw  = ws;
    float* kw  = qw + PROJ;
    float* vw  = kw + PROJ;
    float* att = vw + PROJ;
    float* x2  = att + PROJ;
    float* al  = x2 + PROJ;
    float* be  = al + (size_t)MM * NH;

    dim3 blk(256);
    dim3 gfull(HD / 64, MM / 64);   // (16, 32)
    dim3 gsmall(1, MM / 64);        // (1, 32)

    // Projections
    hipLaunchKernelGGL(gemm_bias_act, gfull, blk, 0, stream, hs, Wq, bq, qw, MM, HD, HH, 0);
    hipLaunchKernelGGL(gemm_bias_act, gfull, blk, 0, stream, hs, Wk, bk, kw, MM, HD, HH, 0);
    hipLaunchKernelGGL(gemm_bias_act, gfull, blk, 0, stream, hs, Wv, bv, vw, MM, HD, HH, 0);
    hipLaunchKernelGGL(gemm_bias_act, gsmall, blk, 0, stream, hs, Wa, (const float*)nullptr, al, MM, NH, HH, 1);
    hipLaunchKernelGGL(gemm_bias_act, gsmall, blk, 0, stream, hs, Wb, (const float*)nullptr, be, MM, NH, HH, 2);

    // Sequential gated delta recurrence: 32 chains
    hipLaunchKernelGGL(gdn_recurrence, dim3(BB * NH), blk, 0, stream, qw, kw, vw, al, be, att);

    // Residual depthwise causal conv on reshaped view
    hipLaunchKernelGGL(conv_residual, dim3(HD / 256, 1024, BB), blk, 0, stream, att, Wconv, x2);

    // Output projection
    hipLaunchKernelGGL(gemm_bias_act, gfull, blk, 0, stream, x2, Wo, bo, out, MM, HH, HD, 0);
}

// Round 3
// 631.538 us; speedup vs baseline: 1.6879x; 1.1754x over previous
//
#include <hip/hip_runtime.h>
#include <math.h>

// Problem constants
#define BB 2
#define LL 1024
#define HH 1024
#define NH 16
#define DD 64
#define KK 4
#define HD (NH * DD)   // 1024
#define MM (BB * LL)   // 2048
#define RCT 32         // recurrence chunk length staged in LDS

// ---------------------------------------------------------------------------
// DPP helpers: 16-lane full reduction via quad_perm xor1, xor2, row_ror:4,
// row_ror:8 (all lanes of each 16-lane row end with the row sum).
// ---------------------------------------------------------------------------
template <int CTRL>
__device__ __forceinline__ float dpp_addf(float x) {
    int y = __builtin_amdgcn_update_dpp(0, __builtin_bit_cast(int, x),
                                        CTRL, 0xF, 0xF, true);
    return x + __builtin_bit_cast(float, y);
}
__device__ __forceinline__ float red16(float x) {
    x = dpp_addf<0xB1>(x);    // quad_perm [1,0,3,2]  (xor 1)
    x = dpp_addf<0x4E>(x);    // quad_perm [2,3,0,1]  (xor 2)
    x = dpp_addf<0x124>(x);   // row_ror:4
    x = dpp_addf<0x128>(x);   // row_ror:8
    return x;
}

// ---------------------------------------------------------------------------
// Fused projection GEMM: z=0/1/2 -> q/k/v = hs @ W^T + b (128x128 tiles),
// z=3 -> ab[m][0:16]=sigmoid(hs@Wa^T), ab[m][16:32]=softplus(hs@Wb^T).
// 256 threads, 8x8 microtile (row/col split groups +0/+64), BK=16, dbuf LDS.
// ---------------------------------------------------------------------------
__global__ __launch_bounds__(256) void fgemm_fused(
    const float* __restrict__ A,
    const float* __restrict__ Wq, const float* __restrict__ bq,
    const float* __restrict__ Wk, const float* __restrict__ bk,
    const float* __restrict__ Wv, const float* __restrict__ bv,
    const float* __restrict__ Wa, const float* __restrict__ Wb,
    float* __restrict__ qw, float* __restrict__ kw, float* __restrict__ vw,
    float* __restrict__ ab)
{
    const int z = blockIdx.z;
    if (z == 3 && blockIdx.x != 0) return;

    __shared__ float As[2][16][132];
    __shared__ float Bs[2][16][132];

    const int tid = threadIdx.x;
    const int bm = blockIdx.y * 128;
    const int bn = blockIdx.x * 128;
    const int tx4 = (tid & 15) * 4;
    const int ty4 = (tid >> 4) * 4;

    // staging: 512 float4 per tile; thread handles f4 #tid and #(tid+256)
    const int r0 = tid >> 2;           // 0..63
    const int r1 = (tid + 256) >> 2;   // 64..127
    const int c0 = (tid & 3) * 4;      // k offset

    const float* Arow0 = A + (size_t)(bm + r0) * HH + c0;
    const float* Arow1 = A + (size_t)(bm + r1) * HH + c0;

    const float* W = nullptr; const float* bias = nullptr; float* C = nullptr;
    if (z == 0)      { W = Wq; bias = bq; C = qw; }
    else if (z == 1) { W = Wk; bias = bk; C = kw; }
    else if (z == 2) { W = Wv; bias = bv; C = vw; }

    const float* Brow0 = nullptr;
    const float* Brow1 = nullptr;
    if (z < 3) {
        Brow0 = W + (size_t)(bn + r0) * HH + c0;
        Brow1 = W + (size_t)(bn + r1) * HH + c0;
    } else {
        if (r0 < 16)      Brow0 = Wa + (size_t)r0 * HH + c0;
        else if (r0 < 32) Brow0 = Wb + (size_t)(r0 - 16) * HH + c0;
        // rows >= 32 (and all of r1) stay zero
    }

    float acc[2][2][4][4] = {};

    float4 a0 = *(const float4*)(Arow0);
    float4 a1 = *(const float4*)(Arow1);
    float4 b0 = Brow0 ? *(const float4*)(Brow0) : make_float4(0.f,0.f,0.f,0.f);
    float4 b1 = Brow1 ? *(const float4*)(Brow1) : make_float4(0.f,0.f,0.f,0.f);

    As[0][c0+0][r0] = a0.x; As[0][c0+1][r0] = a0.y; As[0][c0+2][r0] = a0.z; As[0][c0+3][r0] = a0.w;
    As[0][c0+0][r1] = a1.x; As[0][c0+1][r1] = a1.y; As[0][c0+2][r1] = a1.z; As[0][c0+3][r1] = a1.w;
    Bs[0][c0+0][r0] = b0.x; Bs[0][c0+1][r0] = b0.y; Bs[0][c0+2][r0] = b0.z; Bs[0][c0+3][r0] = b0.w;
    Bs[0][c0+0][r1] = b1.x; Bs[0][c0+1][r1] = b1.y; Bs[0][c0+2][r1] = b1.z; Bs[0][c0+3][r1] = b1.w;
    __syncthreads();

    for (int k0 = 0; k0 < HH; k0 += 16) {
        const int cur = (k0 >> 4) & 1, nxt = cur ^ 1;
        const bool more = (k0 + 16 < HH);
        if (more) {
            a0 = *(const float4*)(Arow0 + k0 + 16);
            a1 = *(const float4*)(Arow1 + k0 + 16);
            b0 = Brow0 ? *(const float4*)(Brow0 + k0 + 16) : make_float4(0.f,0.f,0.f,0.f);
            b1 = Brow1 ? *(const float4*)(Brow1 + k0 + 16) : make_float4(0.f,0.f,0.f,0.f);
        }
        #pragma unroll
        for (int kk = 0; kk < 16; ++kk) {
            float av[2][4], bvv[2][4];
            *(float4*)&av[0][0]  = *(const float4*)&As[cur][kk][ty4];
            *(float4*)&av[1][0]  = *(const float4*)&As[cur][kk][64 + ty4];
            *(float4*)&bvv[0][0] = *(const float4*)&Bs[cur][kk][tx4];
            *(float4*)&bvv[1][0] = *(const float4*)&Bs[cur][kk][64 + tx4];
            #pragma unroll
            for (int rg = 0; rg < 2; ++rg)
            #pragma unroll
            for (int i = 0; i < 4; ++i)
            #pragma unroll
            for (int cg = 0; cg < 2; ++cg)
            #pragma unroll
            for (int j = 0; j < 4; ++j)
                acc[rg][cg][i][j] = fmaf(av[rg][i], bvv[cg][j], acc[rg][cg][i][j]);
        }
        if (more) {
            As[nxt][c0+0][r0] = a0.x; As[nxt][c0+1][r0] = a0.y; As[nxt][c0+2][r0] = a0.z; As[nxt][c0+3][r0] = a0.w;
            As[nxt][c0+0][r1] = a1.x; As[nxt][c0+1][r1] = a1.y; As[nxt][c0+2][r1] = a1.z; As[nxt][c0+3][r1] = a1.w;
            Bs[nxt][c0+0][r0] = b0.x; Bs[nxt][c0+1][r0] = b0.y; Bs[nxt][c0+2][r0] = b0.z; Bs[nxt][c0+3][r0] = b0.w;
            Bs[nxt][c0+0][r1] = b1.x; Bs[nxt][c0+1][r1] = b1.y; Bs[nxt][c0+2][r1] = b1.z; Bs[nxt][c0+3][r1] = b1.w;
        }
        __syncthreads();
    }

    if (z < 3) {
        #pragma unroll
        for (int rg = 0; rg < 2; ++rg)
        #pragma unroll
        for (int i = 0; i < 4; ++i) {
            const int row = bm + rg * 64 + ty4 + i;
            #pragma unroll
            for (int cg = 0; cg < 2; ++cg) {
                const int col = bn + cg * 64 + tx4;
                float4 bb = *(const float4*)(bias + col);
                float4 o;
                o.x = acc[rg][cg][i][0] + bb.x;
                o.y = acc[rg][cg][i][1] + bb.y;
                o.z = acc[rg][cg][i][2] + bb.z;
                o.w = acc[rg][cg][i][3] + bb.w;
                *(float4*)(C + (size_t)row * HH + col) = o;
            }
        }
    } else {
        if (tx4 < 32) {
            const bool sig = (tx4 < 16);
            #pragma unroll
            for (int rg = 0; rg < 2; ++rg)
            #pragma unroll
            for (int i = 0; i < 4; ++i) {
                const int row = bm + rg * 64 + ty4 + i;
                float4 o;
                float vv[4];
                #pragma unroll
                for (int j = 0; j < 4; ++j) {
                    float x = acc[rg][0][i][j];
                    vv[j] = sig ? (1.f / (1.f + expf(-x)))
                                : (fmaxf(x, 0.f) + log1pf(expf(-fabsf(x))));
                }
                o.x = vv[0]; o.y = vv[1]; o.z = vv[2]; o.w = vv[3];
                *(float4*)(ab + (size_t)row * 32 + tx4) = o;
            }
        }
    }
}

// ---------------------------------------------------------------------------
// Output projection GEMM: out = x2 @ Wo^T + bo. 128(M)x64(N) tile, 256 thr,
// 8x4 microtile, BK=16, double-buffered LDS. Grid (16,16) = 256 blocks.
// ---------------------------------------------------------------------------
__global__ __launch_bounds__(256) void fgemm_out(
    const float* __restrict__ A, const float* __restrict__ W,
    const float* __restrict__ bias, float* __restrict__ C)
{
    __shared__ float As[2][16][132];
    __shared__ float Bs[2][16][68];

    const int tid = threadIdx.x;
    const int bm = blockIdx.y * 128;
    const int bn = blockIdx.x * 64;
    const int tx4 = (tid & 15) * 4;
    const int ty4 = (tid >> 4) * 4;

    const int r0 = tid >> 2;
    const int r1 = (tid + 256) >> 2;
    const int c0 = (tid & 3) * 4;

    const float* Arow0 = A + (size_t)(bm + r0) * HH + c0;
    const float* Arow1 = A + (size_t)(bm + r1) * HH + c0;
    const float* Brow  = W + (size_t)(bn + r0) * HH + c0;

    float acc[2][4][4] = {};

    float4 a0 = *(const float4*)(Arow0);
    float4 a1 = *(const float4*)(Arow1);
    float4 b0 = *(const float4*)(Brow);

    As[0][c0+0][r0] = a0.x; As[0][c0+1][r0] = a0.y; As[0][c0+2][r0] = a0.z; As[0][c0+3][r0] = a0.w;
    As[0][c0+0][r1] = a1.x; As[0][c0+1][r1] = a1.y; As[0][c0+2][r1] = a1.z; As[0][c0+3][r1] = a1.w;
    Bs[0][c0+0][r0] = b0.x; Bs[0][c0+1][r0] = b0.y; Bs[0][c0+2][r0] = b0.z; Bs[0][c0+3][r0] = b0.w;
    __syncthreads();

    for (int k0 = 0; k0 < HH; k0 += 16) {
        const int cur = (k0 >> 4) & 1, nxt = cur ^ 1;
        const bool more = (k0 + 16 < HH);
        if (more) {
            a0 = *(const float4*)(Arow0 + k0 + 16);
            a1 = *(const float4*)(Arow1 + k0 + 16);
            b0 = *(const float4*)(Brow + k0 + 16);
        }
        #pragma unroll
        for (int kk = 0; kk < 16; ++kk) {
            float av[2][4], bvv[4];
            *(float4*)&av[0][0] = *(const float4*)&As[cur][kk][ty4];
            *(float4*)&av[1][0] = *(const float4*)&As[cur][kk][64 + ty4];
            *(float4*)&bvv[0]   = *(const float4*)&Bs[cur][kk][tx4];
            #pragma unroll
            for (int rg = 0; rg < 2; ++rg)
            #pragma unroll
            for (int i = 0; i < 4; ++i)
            #pragma unroll
            for (int j = 0; j < 4; ++j)
                acc[rg][i][j] = fmaf(av[rg][i], bvv[j], acc[rg][i][j]);
        }
        if (more) {
            As[nxt][c0+0][r0] = a0.x; As[nxt][c0+1][r0] = a0.y; As[nxt][c0+2][r0] = a0.z; As[nxt][c0+3][r0] = a0.w;
            As[nxt][c0+0][r1] = a1.x; As[nxt][c0+1][r1] = a1.y; As[nxt][c0+2][r1] = a1.z; As[nxt][c0+3][r1] = a1.w;
            Bs[nxt][c0+0][r0] = b0.x; Bs[nxt][c0+1][r0] = b0.y; Bs[nxt][c0+2][r0] = b0.z; Bs[nxt][c0+3][r0] = b0.w;
        }
        __syncthreads();
    }

    const int col = bn + tx4;
    float4 bb = *(const float4*)(bias + col);
    #pragma unroll
    for (int rg = 0; rg < 2; ++rg)
    #pragma unroll
    for (int i = 0; i < 4; ++i) {
        const int row = bm + rg * 64 + ty4 + i;
        float4 o;
        o.x = acc[rg][i][0] + bb.x;
        o.y = acc[rg][i][1] + bb.y;
        o.z = acc[rg][i][2] + bb.z;
        o.w = acc[rg][i][3] + bb.w;
        *(float4*)(C + (size_t)row * HH + col) = o;
    }
}

// ---------------------------------------------------------------------------
// Gated delta recurrence, row-split. 512 blocks x 64 threads (1 wave).
// Block = (chain bh, row-slice s): owns 4 state rows. Lane: rl = lane>>4
// (local row), el = lane&15 (e-slice of 4). S[r][e0..e0+3] in 4 VGPRs.
// k/q (full 64-vec), v (4 rows), alpha/beta staged in LDS per 32-step chunk,
// double-buffered; global prefetch of chunk c+1 issues before chunk c compute.
// ---------------------------------------------------------------------------
__global__ __launch_bounds__(64) void gdn_recurrence(
    const float* __restrict__ qw, const float* __restrict__ kw,
    const float* __restrict__ vw, const float* __restrict__ ab,
    float* __restrict__ att)
{
    __shared__ float ks[2][RCT][64];
    __shared__ float qs[2][RCT][64];
    __shared__ float vs_[2][RCT][4];
    __shared__ float as_[2][RCT];
    __shared__ float bs_[2][RCT];

    const int blk = blockIdx.x;   // 0..511
    const int bh = blk >> 4;
    const int s  = blk & 15;
    const int b  = bh >> 4;
    const int h  = bh & 15;
    const int lane = threadIdx.x;
    const int rl = lane >> 4;     // 0..3 local row
    const int el = lane & 15;
    const int e0 = el * 4;
    const int r0 = s * 4;
    const int r  = r0 + rl;

    const float* kb  = kw + ((size_t)b * LL) * HD + h * DD;
    const float* qb  = qw + ((size_t)b * LL) * HD + h * DD;
    const float* vb  = vw + ((size_t)b * LL) * HD + h * DD + r0;
    const float* abp = ab + ((size_t)b * LL) * 32 + h;
    float* op = att + (((size_t)(b * NH + h)) * LL) * DD + r;

    float S0 = 0.f, S1 = 0.f, S2 = 0.f, S3 = 0.f;

    // ---- stage chunk 0 into buffer 0 ----
    #pragma unroll
    for (int i = 0; i < 8; ++i) {
        const int idx = i * 64 + lane;
        const int t = idx >> 4, c4 = (idx & 15) * 4;
        *(float4*)&ks[0][t][c4] = *(const float4*)(kb + (size_t)t * HD + c4);
        *(float4*)&qs[0][t][c4] = *(const float4*)(qb + (size_t)t * HD + c4);
    }
    if (lane < RCT) {
        *(float4*)&vs_[0][lane][0] = *(const float4*)(vb + (size_t)lane * HD);
        as_[0][lane] = abp[(size_t)lane * 32];
        bs_[0][lane] = abp[(size_t)lane * 32 + 16];
    }
    __syncthreads();

    for (int c = 0; c < LL / RCT; ++c) {
        const int cur = c & 1, nxt = cur ^ 1;
        const bool more = (c + 1 < LL / RCT);

        // global prefetch chunk c+1 into registers (latency covered by compute)
        float4 pk[8], pq[8], pv = make_float4(0.f,0.f,0.f,0.f);
        float pa = 0.f, pb2 = 0.f;
        if (more) {
            const size_t t0 = (size_t)(c + 1) * RCT;
            #pragma unroll
            for (int i = 0; i < 8; ++i) {
                const int idx = i * 64 + lane;
                const int t = idx >> 4, c4 = (idx & 15) * 4;
                pk[i] = *(const float4*)(kb + (t0 + t) * HD + c4);
                pq[i] = *(const float4*)(qb + (t0 + t) * HD + c4);
            }
            if (lane < RCT) {
                pv  = *(const float4*)(vb + (t0 + lane) * HD);
                pa  = abp[(t0 + lane) * 32];
                pb2 = abp[(t0 + lane) * 32 + 16];
            }
        }

        // 32 steps from buffer cur, 1-step LDS->reg prefetch
        float4 kc = *(const float4*)&ks[cur][0][e0];
        float4 qc = *(const float4*)&qs[cur][0][e0];
        float vc = vs_[cur][0][rl];
        float ac = as_[cur][0];
        float bc = bs_[cur][0];

        #pragma unroll 4
        for (int t = 0; t < RCT; ++t) {
            const int tn = (t + 1) & (RCT - 1);
            float4 kn = *(const float4*)&ks[cur][tn][e0];
            float4 qn = *(const float4*)&qs[cur][tn][e0];
            const float vn  = vs_[cur][tn][rl];
            const float an  = as_[cur][tn];
            const float bn2 = bs_[cur][tn];

            // sk = (S . k) for this row
            float p0 = fmaf(S1, kc.y, S0 * kc.x);
            float p1 = fmaf(S3, kc.w, S2 * kc.z);
            float sk = red16(p0 + p1);

            const float cf = bc * fmaf(-ac, sk, vc);

            S0 = fmaf(ac, S0, cf * kc.x);
            S1 = fmaf(ac, S1, cf * kc.y);
            S2 = fmaf(ac, S2, cf * kc.z);
            S3 = fmaf(ac, S3, cf * kc.w);

            float q0 = fmaf(S1, qc.y, S0 * qc.x);
            float q1 = fmaf(S3, qc.w, S2 * qc.z);
            float o = red16(q0 + q1);
            if (el == 0) op[(size_t)(c * RCT + t) * DD] = o;

            kc = kn; qc = qn; vc = vn; ac = an; bc = bn2;
        }

        // commit prefetched chunk to the other buffer
        if (more) {
            #pragma unroll
            for (int i = 0; i < 8; ++i) {
                const int idx = i * 64 + lane;
                const int t = idx >> 4, c4 = (idx & 15) * 4;
                *(float4*)&ks[nxt][t][c4] = pk[i];
                *(float4*)&qs[nxt][t][c4] = pq[i];
            }
            if (lane < RCT) {
                *(float4*)&vs_[nxt][lane][0] = pv;
                as_[nxt][lane] = pa;
                bs_[nxt][lane] = pb2;
            }
        }
        __syncthreads();
    }
}

// ---------------------------------------------------------------------------
// Residual depthwise causal conv on the bug-compatible reshaped view.
// ---------------------------------------------------------------------------
__global__ __launch_bounds__(256) void conv_residual(
    const float* __restrict__ y, const float* __restrict__ Wc,
    float* __restrict__ x2)
{
    const int c = blockIdx.x * 256 + threadIdx.x;
    const int i = blockIdx.y;
    const int b = blockIdx.z;
    const size_t rowbase = ((size_t)b * 1024 + i) * 1024;

    float w0 = Wc[c * 4 + 0], w1 = Wc[c * 4 + 1];
    float w2 = Wc[c * 4 + 2], w3 = Wc[c * 4 + 3];

    float ycur = y[rowbase + c];
    float acc = ycur + w3 * ycur;
    if (i >= 1) acc = fmaf(w2, y[rowbase - 1024 + c], acc);
    if (i >= 2) acc = fmaf(w1, y[rowbase - 2048 + c], acc);
    if (i >= 3) acc = fmaf(w0, y[rowbase - 3072 + c], acc);
    x2[rowbase + c] = acc;
}

// ---------------------------------------------------------------------------
extern "C" void kernel_launch(void* const* d_in, const int* in_sizes, int n_in,
                              void* d_out, int out_size, void* d_ws, size_t ws_size,
                              hipStream_t stream)
{
    const float* hs    = (const float*)d_in[0];
    const float* Wq    = (const float*)d_in[1];
    const float* bq    = (const float*)d_in[2];
    const float* Wk    = (const float*)d_in[3];
    const float* bk    = (const float*)d_in[4];
    const float* Wv    = (const float*)d_in[5];
    const float* bv    = (const float*)d_in[6];
    const float* Wa    = (const float*)d_in[7];
    const float* Wb    = (const float*)d_in[8];
    const float* Wconv = (const float*)d_in[9];
    const float* Wo    = (const float*)d_in[10];
    const float* bo    = (const float*)d_in[11];
    float* out = (float*)d_out;

    float* ws = (float*)d_ws;
    const size_t PROJ = (size_t)MM * HD;   // 2048*1024
    float* qw  = ws;
    float* kw  = qw + PROJ;
    float* vw  = kw + PROJ;
    float* att = vw + PROJ;
    float* x2  = att + PROJ;
    float* abw = x2 + PROJ;                // [2048][32]: cols 0-15 alpha, 16-31 beta

    // Fused projections: q, k, v (z=0..2) + alpha/beta (z=3)
    hipLaunchKernelGGL(fgemm_fused, dim3(8, 16, 4), dim3(256), 0, stream,
                       hs, Wq, bq, Wk, bk, Wv, bv, Wa, Wb, qw, kw, vw, abw);

    // Gated delta recurrence: 32 chains x 16 row-slices = 512 one-wave blocks
    hipLaunchKernelGGL(gdn_recurrence, dim3(512), dim3(64), 0, stream,
                       qw, kw, vw, abw, att);

    // Residual depthwise causal conv on reshaped view
    hipLaunchKernelGGL(conv_residual, dim3(HD / 256, 1024, BB), dim3(256), 0, stream,
                       att, Wconv, x2);

    // Output projection
    hipLaunchKernelGGL(fgemm_out, dim3(16, 16), dim3(256), 0, stream,
                       x2, Wo, bo, out);
}

// Round 4
// 442.006 us; speedup vs baseline: 2.4116x; 1.4288x over previous
//
#include <hip/hip_runtime.h>
#include <math.h>

// Problem constants
#define BB 2
#define LL 1024
#define HH 1024
#define NH 16
#define DD 64
#define HD (NH * DD)   // 1024
#define MM (BB * LL)   // 2048
#define RCT 32         // recurrence chunk length staged in LDS
#define KEXT 3072      // extended K for f16 hi/lo split GEMM (3 x 1024)
#define NB_QKV 3200    // Be rows: 3072 qkv + 32 alpha/beta + 96 zero pad

typedef _Float16 f16x8 __attribute__((ext_vector_type(8)));
typedef _Float16 f16x4 __attribute__((ext_vector_type(4)));
typedef float f32x4 __attribute__((ext_vector_type(4)));

// ---------------------------------------------------------------------------
// async global->LDS, 16B per lane; LDS dest = wave-uniform base + lane*16
// ---------------------------------------------------------------------------
__device__ __forceinline__ void load_lds16(const void* g, void* l) {
    __builtin_amdgcn_global_load_lds(
        (const __attribute__((address_space(1))) void*)g,
        (__attribute__((address_space(3))) void*)l, 16, 0, 0);
}

// ---------------------------------------------------------------------------
// Split-f16 conversion kernels. x = hi + lo exactly captures ~22 mantissa
// bits; power-of-2 pre-scales keep lo out of f16-subnormal range.
// A-side layout along Kext: [hi | lo | hi]; B-side: [hi | hi | lo]
// => sum over Kext = hi*hi + lo*hi + hi*lo  (missing lo*lo ~ 2^-22 rel).
// ---------------------------------------------------------------------------
__global__ __launch_bounds__(256) void convert_A(
    const float* __restrict__ X, _Float16* __restrict__ Ae, float scale)
{
    const int row = blockIdx.x;
    const int t = threadIdx.x;
    float4 x = *(const float4*)(X + (size_t)row * 1024 + t * 4);
    x.x *= scale; x.y *= scale; x.z *= scale; x.w *= scale;
    f16x4 h, l;
    h[0] = (_Float16)x.x; l[0] = (_Float16)(x.x - (float)h[0]);
    h[1] = (_Float16)x.y; l[1] = (_Float16)(x.y - (float)h[1]);
    h[2] = (_Float16)x.z; l[2] = (_Float16)(x.z - (float)h[2]);
    h[3] = (_Float16)x.w; l[3] = (_Float16)(x.w - (float)h[3]);
    _Float16* base = Ae + (size_t)row * KEXT + t * 4;
    *(f16x4*)(base)        = h;
    *(f16x4*)(base + 1024) = l;
    *(f16x4*)(base + 2048) = h;
}

__global__ __launch_bounds__(256) void convert_Wqkv(
    const float* __restrict__ Wq, const float* __restrict__ Wk,
    const float* __restrict__ Wv, const float* __restrict__ Wa,
    const float* __restrict__ Wb, _Float16* __restrict__ Be)
{
    const int n = blockIdx.x;
    const int t = threadIdx.x;
    const float* src = nullptr;
    if (n < 1024)      src = Wq + (size_t)n * 1024;
    else if (n < 2048) src = Wk + (size_t)(n - 1024) * 1024;
    else if (n < 3072) src = Wv + (size_t)(n - 2048) * 1024;
    else if (n < 3088) src = Wa + (size_t)(n - 3072) * 1024;
    else if (n < 3104) src = Wb + (size_t)(n - 3088) * 1024;
    float4 x = src ? *(const float4*)(src + t * 4) : make_float4(0.f,0.f,0.f,0.f);
    x.x *= 64.f; x.y *= 64.f; x.z *= 64.f; x.w *= 64.f;
    f16x4 h, l;
    h[0] = (_Float16)x.x; l[0] = (_Float16)(x.x - (float)h[0]);
    h[1] = (_Float16)x.y; l[1] = (_Float16)(x.y - (float)h[1]);
    h[2] = (_Float16)x.z; l[2] = (_Float16)(x.z - (float)h[2]);
    h[3] = (_Float16)x.w; l[3] = (_Float16)(x.w - (float)h[3]);
    _Float16* base = Be + (size_t)n * KEXT + t * 4;
    *(f16x4*)(base)        = h;
    *(f16x4*)(base + 1024) = h;
    *(f16x4*)(base + 2048) = l;
}

__global__ __launch_bounds__(256) void convert_Wo(
    const float* __restrict__ Wo, _Float16* __restrict__ Be)
{
    const int n = blockIdx.x;
    const int t = threadIdx.x;
    float4 x = *(const float4*)(Wo + (size_t)n * 1024 + t * 4);
    x.x *= 64.f; x.y *= 64.f; x.z *= 64.f; x.w *= 64.f;
    f16x4 h, l;
    h[0] = (_Float16)x.x; l[0] = (_Float16)(x.x - (float)h[0]);
    h[1] = (_Float16)x.y; l[1] = (_Float16)(x.y - (float)h[1]);
    h[2] = (_Float16)x.z; l[2] = (_Float16)(x.z - (float)h[2]);
    h[3] = (_Float16)x.w; l[3] = (_Float16)(x.w - (float)h[3]);
    _Float16* base = Be + (size_t)n * KEXT + t * 4;
    *(f16x4*)(base)        = h;
    *(f16x4*)(base + 1024) = h;
    *(f16x4*)(base + 2048) = l;
}

// ---------------------------------------------------------------------------
// MFMA GEMM (m97 structure): C[M,Ntiles*128] = Ae[M,KEXT] @ Be[N,KEXT]^T.
// 128x128 tile, 256 thr = 4 waves, each wave 64x64 (4x4 tiles of 16x16x32).
// mode 0: epilogue scale 1/1024 -> qkv cols 0..3071 (+bias), cols 3072..3103
//         -> ab with sigmoid/softplus. mode 1: scale 64, +bo -> out.
// ---------------------------------------------------------------------------
__global__ __launch_bounds__(256) void mfma_gemm(
    const _Float16* __restrict__ Ae, const _Float16* __restrict__ Be,
    float* __restrict__ qkv, float* __restrict__ ab,
    const float* __restrict__ bq, const float* __restrict__ bk,
    const float* __restrict__ bv,
    float* __restrict__ outp, const float* __restrict__ bo, int mode)
{
    __shared__ __align__(16) _Float16 As[128 * 32];
    __shared__ __align__(16) _Float16 Bs[128 * 32];

    const int tid = threadIdx.x;
    const int wave = tid >> 6;
    const int lane = tid & 63;
    const int bm = blockIdx.y * 128;
    const int bn = blockIdx.x * 128;
    const int wr = (wave >> 1) * 64;   // m offset of wave in tile
    const int wc = (wave & 1) * 64;    // n offset

    // staging: wave handles 32 rows (2 issues x 16 rows x 4 lanes)
    const int srow = lane >> 2;            // 0..15
    const int scol = (lane & 3) * 8;       // f16 col offset
    const _Float16* gA0 = Ae + (size_t)(bm + wave * 32 + srow) * KEXT + scol;
    const _Float16* gA1 = gA0 + (size_t)16 * KEXT;
    const _Float16* gB0 = Be + (size_t)(bn + wave * 32 + srow) * KEXT + scol;
    const _Float16* gB1 = gB0 + (size_t)16 * KEXT;
    _Float16* lA0 = &As[(wave * 32) * 32];
    _Float16* lA1 = &As[(wave * 32 + 16) * 32];
    _Float16* lB0 = &Bs[(wave * 32) * 32];
    _Float16* lB1 = &Bs[(wave * 32 + 16) * 32];

    const int fm = lane & 15;          // row within 16-tile
    const int fq = (lane >> 4) * 8;    // k offset of this lane's frag

    f32x4 acc[4][4] = {};

    for (int k0 = 0; k0 < KEXT; k0 += 32) {
        load_lds16(gA0 + k0, lA0);
        load_lds16(gA1 + k0, lA1);
        load_lds16(gB0 + k0, lB0);
        load_lds16(gB1 + k0, lB1);
        __syncthreads();

        f16x8 a[4], b[4];
        #pragma unroll
        for (int mt = 0; mt < 4; ++mt)
            a[mt] = *(const f16x8*)&As[(wr + mt * 16 + fm) * 32 + fq];
        #pragma unroll
        for (int nt = 0; nt < 4; ++nt)
            b[nt] = *(const f16x8*)&Bs[(wc + nt * 16 + fm) * 32 + fq];
        #pragma unroll
        for (int mt = 0; mt < 4; ++mt)
            #pragma unroll
            for (int nt = 0; nt < 4; ++nt)
                acc[mt][nt] = __builtin_amdgcn_mfma_f32_16x16x32_f16(
                    a[mt], b[nt], acc[mt][nt], 0, 0, 0);
        __syncthreads();
    }

    const int rquad = (lane >> 4) * 4;
    #pragma unroll
    for (int mt = 0; mt < 4; ++mt) {
        #pragma unroll
        for (int nt = 0; nt < 4; ++nt) {
            const int col = bn + wc + nt * 16 + fm;
            #pragma unroll
            for (int i = 0; i < 4; ++i) {
                const int row = bm + wr + mt * 16 + rquad + i;
                float val = acc[mt][nt][i];
                if (mode == 0) {
                    val *= (1.0f / 1024.0f);   // undo hs*16, W*64
                    if (col < 1024)
                        qkv[(size_t)row * 3072 + col] = val + bq[col];
                    else if (col < 2048)
                        qkv[(size_t)row * 3072 + col] = val + bk[col - 1024];
                    else if (col < 3072)
                        qkv[(size_t)row * 3072 + col] = val + bv[col - 2048];
                    else {
                        const int c = col - 3072;
                        if (c < 16)
                            ab[(size_t)row * 32 + c] = 1.f / (1.f + expf(-val));
                        else if (c < 32)
                            ab[(size_t)row * 32 + c] =
                                fmaxf(val, 0.f) + log1pf(expf(-fabsf(val)));
                    }
                } else {
                    // undo x2*2^-12, W*64 => *64
                    outp[(size_t)row * 1024 + col] = val * 64.f + bo[col];
                }
            }
        }
    }
}

// ---------------------------------------------------------------------------
// DPP 16-lane reduction
// ---------------------------------------------------------------------------
template <int CTRL>
__device__ __forceinline__ float dpp_addf(float x) {
    int y = __builtin_amdgcn_update_dpp(0, __builtin_bit_cast(int, x),
                                        CTRL, 0xF, 0xF, true);
    return x + __builtin_bit_cast(float, y);
}
__device__ __forceinline__ float red16(float x) {
    x = dpp_addf<0xB1>(x);
    x = dpp_addf<0x4E>(x);
    x = dpp_addf<0x124>(x);
    x = dpp_addf<0x128>(x);
    return x;
}

// ---------------------------------------------------------------------------
// Gated delta recurrence, row-split. 512 blocks x 64 threads.
// q/k/v now read from the fused qkv buffer [2048][3072] (q|k|v).
// ---------------------------------------------------------------------------
__global__ __launch_bounds__(64) void gdn_recurrence(
    const float* __restrict__ qkv, const float* __restrict__ ab,
    float* __restrict__ att)
{
    __shared__ float ks[2][RCT][64];
    __shared__ float qs[2][RCT][64];
    __shared__ float vs_[2][RCT][4];
    __shared__ float as_[2][RCT];
    __shared__ float bs_[2][RCT];

    const int blk = blockIdx.x;
    const int bh = blk >> 4;
    const int s  = blk & 15;
    const int b  = bh >> 4;
    const int h  = bh & 15;
    const int lane = threadIdx.x;
    const int rl = lane >> 4;
    const int el = lane & 15;
    const int e0 = el * 4;
    const int r0 = s * 4;
    const int r  = r0 + rl;

    const float* qb  = qkv + (size_t)b * LL * 3072 + h * DD;
    const float* kb  = qb + 1024;
    const float* vb  = qb + 2048 + r0;
    const float* abp = ab + (size_t)b * LL * 32 + h;
    float* op = att + (((size_t)(b * NH + h)) * LL) * DD + r;

    float S0 = 0.f, S1 = 0.f, S2 = 0.f, S3 = 0.f;

    #pragma unroll
    for (int i = 0; i < 8; ++i) {
        const int idx = i * 64 + lane;
        const int t = idx >> 4, c4 = (idx & 15) * 4;
        *(float4*)&ks[0][t][c4] = *(const float4*)(kb + (size_t)t * 3072 + c4);
        *(float4*)&qs[0][t][c4] = *(const float4*)(qb + (size_t)t * 3072 + c4);
    }
    if (lane < RCT) {
        *(float4*)&vs_[0][lane][0] = *(const float4*)(vb + (size_t)lane * 3072);
        as_[0][lane] = abp[(size_t)lane * 32];
        bs_[0][lane] = abp[(size_t)lane * 32 + 16];
    }
    __syncthreads();

    for (int c = 0; c < LL / RCT; ++c) {
        const int cur = c & 1, nxt = cur ^ 1;
        const bool more = (c + 1 < LL / RCT);

        float4 pk[8], pq[8], pv = make_float4(0.f,0.f,0.f,0.f);
        float pa = 0.f, pb2 = 0.f;
        if (more) {
            const size_t t0 = (size_t)(c + 1) * RCT;
            #pragma unroll
            for (int i = 0; i < 8; ++i) {
                const int idx = i * 64 + lane;
                const int t = idx >> 4, c4 = (idx & 15) * 4;
                pk[i] = *(const float4*)(kb + (t0 + t) * 3072 + c4);
                pq[i] = *(const float4*)(qb + (t0 + t) * 3072 + c4);
            }
            if (lane < RCT) {
                pv  = *(const float4*)(vb + (t0 + lane) * 3072);
                pa  = abp[(t0 + lane) * 32];
                pb2 = abp[(t0 + lane) * 32 + 16];
            }
        }

        float4 kc = *(const float4*)&ks[cur][0][e0];
        float4 qc = *(const float4*)&qs[cur][0][e0];
        float vc = vs_[cur][0][rl];
        float ac = as_[cur][0];
        float bc = bs_[cur][0];

        #pragma unroll 4
        for (int t = 0; t < RCT; ++t) {
            const int tn = (t + 1) & (RCT - 1);
            float4 kn = *(const float4*)&ks[cur][tn][e0];
            float4 qn = *(const float4*)&qs[cur][tn][e0];
            const float vn  = vs_[cur][tn][rl];
            const float an  = as_[cur][tn];
            const float bn2 = bs_[cur][tn];

            float p0 = fmaf(S1, kc.y, S0 * kc.x);
            float p1 = fmaf(S3, kc.w, S2 * kc.z);
            float sk = red16(p0 + p1);

            const float cf = bc * fmaf(-ac, sk, vc);

            S0 = fmaf(ac, S0, cf * kc.x);
            S1 = fmaf(ac, S1, cf * kc.y);
            S2 = fmaf(ac, S2, cf * kc.z);
            S3 = fmaf(ac, S3, cf * kc.w);

            float q0 = fmaf(S1, qc.y, S0 * qc.x);
            float q1 = fmaf(S3, qc.w, S2 * qc.z);
            float o = red16(q0 + q1);
            if (el == 0) op[(size_t)(c * RCT + t) * DD] = o;

            kc = kn; qc = qn; vc = vn; ac = an; bc = bn2;
        }

        if (more) {
            #pragma unroll
            for (int i = 0; i < 8; ++i) {
                const int idx = i * 64 + lane;
                const int t = idx >> 4, c4 = (idx & 15) * 4;
                *(float4*)&ks[nxt][t][c4] = pk[i];
                *(float4*)&qs[nxt][t][c4] = pq[i];
            }
            if (lane < RCT) {
                *(float4*)&vs_[nxt][lane][0] = pv;
                as_[nxt][lane] = pa;
                bs_[nxt][lane] = pb2;
            }
        }
        __syncthreads();
    }
}

// ---------------------------------------------------------------------------
// Residual depthwise causal conv on the bug-compatible reshaped view.
// ---------------------------------------------------------------------------
__global__ __launch_bounds__(256) void conv_residual(
    const float* __restrict__ y, const float* __restrict__ Wc,
    float* __restrict__ x2)
{
    const int c = blockIdx.x * 256 + threadIdx.x;
    const int i = blockIdx.y;
    const int b = blockIdx.z;
    const size_t rowbase = ((size_t)b * 1024 + i) * 1024;

    float w0 = Wc[c * 4 + 0], w1 = Wc[c * 4 + 1];
    float w2 = Wc[c * 4 + 2], w3 = Wc[c * 4 + 3];

    float ycur = y[rowbase + c];
    float acc = ycur + w3 * ycur;
    if (i >= 1) acc = fmaf(w2, y[rowbase - 1024 + c], acc);
    if (i >= 2) acc = fmaf(w1, y[rowbase - 2048 + c], acc);
    if (i >= 3) acc = fmaf(w0, y[rowbase - 3072 + c], acc);
    x2[rowbase + c] = acc;
}

// ---------------------------------------------------------------------------
extern "C" void kernel_launch(void* const* d_in, const int* in_sizes, int n_in,
                              void* d_out, int out_size, void* d_ws, size_t ws_size,
                              hipStream_t stream)
{
    const float* hs    = (const float*)d_in[0];
    const float* Wq    = (const float*)d_in[1];
    const float* bq    = (const float*)d_in[2];
    const float* Wk    = (const float*)d_in[3];
    const float* bk    = (const float*)d_in[4];
    const float* Wv    = (const float*)d_in[5];
    const float* bv    = (const float*)d_in[6];
    const float* Wa    = (const float*)d_in[7];
    const float* Wb    = (const float*)d_in[8];
    const float* Wconv = (const float*)d_in[9];
    const float* Wo    = (const float*)d_in[10];
    const float* bo    = (const float*)d_in[11];
    float* out = (float*)d_out;

    // workspace layout (bytes)
    char* w = (char*)d_ws;
    float* qkv = (float*)w;                 w += (size_t)MM * 3072 * 4;   // 25.2 MB
    float* att = (float*)w;                 w += (size_t)MM * 1024 * 4;   //  8.4 MB
    float* x2  = (float*)w;                 w += (size_t)MM * 1024 * 4;   //  8.4 MB
    float* ab  = (float*)w;                 w += (size_t)MM * 32 * 4;     //  0.26 MB
    _Float16* Ae = (_Float16*)w;            w += (size_t)MM * KEXT * 2;   // 12.6 MB
    _Float16* Be = (_Float16*)w;            w += (size_t)NB_QKV * KEXT * 2; // 19.7 MB

    // 1) split-f16 conversions for the fused qkv/alpha/beta GEMM
    hipLaunchKernelGGL(convert_A, dim3(MM), dim3(256), 0, stream, hs, Ae, 16.f);
    hipLaunchKernelGGL(convert_Wqkv, dim3(NB_QKV), dim3(256), 0, stream,
                       Wq, Wk, Wv, Wa, Wb, Be);

    // 2) fused q/k/v/alpha/beta projection via f16-split MFMA
    hipLaunchKernelGGL(mfma_gemm, dim3(NB_QKV / 128, MM / 128), dim3(256), 0, stream,
                       Ae, Be, qkv, ab, bq, bk, bv, (float*)nullptr, (const float*)nullptr, 0);

    // 3) gated delta recurrence (fp32, 512 one-wave blocks)
    hipLaunchKernelGGL(gdn_recurrence, dim3(512), dim3(64), 0, stream, qkv, ab, att);

    // 4) residual depthwise causal conv
    hipLaunchKernelGGL(conv_residual, dim3(4, 1024, BB), dim3(256), 0, stream,
                       att, Wconv, x2);

    // 5) out-projection: convert x2 (scaled 2^-12) and Wo, reuse Ae/Be
    hipLaunchKernelGGL(convert_A, dim3(MM), dim3(256), 0, stream, x2, Ae, 1.f / 4096.f);
    hipLaunchKernelGGL(convert_Wo, dim3(1024), dim3(256), 0, stream, Wo, Be);
    hipLaunchKernelGGL(mfma_gemm, dim3(1024 / 128, MM / 128), dim3(256), 0, stream,
                       Ae, Be, (float*)nullptr, (float*)nullptr,
                       (const float*)nullptr, (const float*)nullptr, (const float*)nullptr,
                       out, bo, 1);
}

// Round 5
// 373.114 us; speedup vs baseline: 2.8569x; 1.1846x over previous
//
#include <hip/hip_runtime.h>
#include <math.h>

// Problem constants
#define BB 2
#define LL 1024
#define HH 1024
#define NH 16
#define DD 64
#define HD (NH * DD)   // 1024
#define MM (BB * LL)   // 2048
#define RCT 32         // recurrence chunk length staged in LDS
#define KEXT 3072      // extended K for f16 hi/lo split GEMM (3 x 1024)
#define NB_QKV 3200    // Be rows: 3072 qkv + 32 alpha/beta + 96 zero pad

typedef _Float16 f16x8 __attribute__((ext_vector_type(8)));
typedef _Float16 f16x4 __attribute__((ext_vector_type(4)));
typedef float f32x4 __attribute__((ext_vector_type(4)));

// ---------------------------------------------------------------------------
// async global->LDS, 16B per lane; LDS dest = wave-uniform base + lane*16
// (per-lane global gather addresses are allowed — verified by round-4 GEMM)
// ---------------------------------------------------------------------------
__device__ __forceinline__ void load_lds16(const void* g, void* l) {
    __builtin_amdgcn_global_load_lds(
        (const __attribute__((address_space(1))) void*)g,
        (__attribute__((address_space(3))) void*)l, 16, 0, 0);
}

// ---------------------------------------------------------------------------
// Split-f16 conversion kernels. x = hi + lo captures ~22 mantissa bits.
// A-side along Kext: [hi | lo | hi]; B-side: [hi | hi | lo]
// => dot = hi*hi + lo*hi + hi*lo (missing lo*lo ~ 2^-22 rel).
// ---------------------------------------------------------------------------
__global__ __launch_bounds__(256) void convert_A(
    const float* __restrict__ X, _Float16* __restrict__ Ae, float scale)
{
    const int row = blockIdx.x;
    const int t = threadIdx.x;
    float4 x = *(const float4*)(X + (size_t)row * 1024 + t * 4);
    x.x *= scale; x.y *= scale; x.z *= scale; x.w *= scale;
    f16x4 h, l;
    h[0] = (_Float16)x.x; l[0] = (_Float16)(x.x - (float)h[0]);
    h[1] = (_Float16)x.y; l[1] = (_Float16)(x.y - (float)h[1]);
    h[2] = (_Float16)x.z; l[2] = (_Float16)(x.z - (float)h[2]);
    h[3] = (_Float16)x.w; l[3] = (_Float16)(x.w - (float)h[3]);
    _Float16* base = Ae + (size_t)row * KEXT + t * 4;
    *(f16x4*)(base)        = h;
    *(f16x4*)(base + 1024) = l;
    *(f16x4*)(base + 2048) = h;
}

__global__ __launch_bounds__(256) void convert_Wqkv(
    const float* __restrict__ Wq, const float* __restrict__ Wk,
    const float* __restrict__ Wv, const float* __restrict__ Wa,
    const float* __restrict__ Wb, _Float16* __restrict__ Be)
{
    const int n = blockIdx.x;
    const int t = threadIdx.x;
    const float* src = nullptr;
    if (n < 1024)      src = Wq + (size_t)n * 1024;
    else if (n < 2048) src = Wk + (size_t)(n - 1024) * 1024;
    else if (n < 3072) src = Wv + (size_t)(n - 2048) * 1024;
    else if (n < 3088) src = Wa + (size_t)(n - 3072) * 1024;
    else if (n < 3104) src = Wb + (size_t)(n - 3088) * 1024;
    float4 x = src ? *(const float4*)(src + t * 4) : make_float4(0.f,0.f,0.f,0.f);
    x.x *= 64.f; x.y *= 64.f; x.z *= 64.f; x.w *= 64.f;
    f16x4 h, l;
    h[0] = (_Float16)x.x; l[0] = (_Float16)(x.x - (float)h[0]);
    h[1] = (_Float16)x.y; l[1] = (_Float16)(x.y - (float)h[1]);
    h[2] = (_Float16)x.z; l[2] = (_Float16)(x.z - (float)h[2]);
    h[3] = (_Float16)x.w; l[3] = (_Float16)(x.w - (float)h[3]);
    _Float16* base = Be + (size_t)n * KEXT + t * 4;
    *(f16x4*)(base)        = h;
    *(f16x4*)(base + 1024) = h;
    *(f16x4*)(base + 2048) = l;
}

__global__ __launch_bounds__(256) void convert_Wo(
    const float* __restrict__ Wo, _Float16* __restrict__ Be)
{
    const int n = blockIdx.x;
    const int t = threadIdx.x;
    float4 x = *(const float4*)(Wo + (size_t)n * 1024 + t * 4);
    x.x *= 64.f; x.y *= 64.f; x.z *= 64.f; x.w *= 64.f;
    f16x4 h, l;
    h[0] = (_Float16)x.x; l[0] = (_Float16)(x.x - (float)h[0]);
    h[1] = (_Float16)x.y; l[1] = (_Float16)(x.y - (float)h[1]);
    h[2] = (_Float16)x.z; l[2] = (_Float16)(x.z - (float)h[2]);
    h[3] = (_Float16)x.w; l[3] = (_Float16)(x.w - (float)h[3]);
    _Float16* base = Be + (size_t)n * KEXT + t * 4;
    *(f16x4*)(base)        = h;
    *(f16x4*)(base + 1024) = h;
    *(f16x4*)(base + 2048) = l;
}

// ---------------------------------------------------------------------------
// MFMA GEMM: C[M,Ntiles*128] = Ae[M,KEXT] @ Be[N,KEXT]^T (unchanged).
// ---------------------------------------------------------------------------
__global__ __launch_bounds__(256) void mfma_gemm(
    const _Float16* __restrict__ Ae, const _Float16* __restrict__ Be,
    float* __restrict__ qkv, float* __restrict__ ab,
    const float* __restrict__ bq, const float* __restrict__ bk,
    const float* __restrict__ bv,
    float* __restrict__ outp, const float* __restrict__ bo, int mode)
{
    __shared__ __align__(16) _Float16 As[128 * 32];
    __shared__ __align__(16) _Float16 Bs[128 * 32];

    const int tid = threadIdx.x;
    const int wave = tid >> 6;
    const int lane = tid & 63;
    const int bm = blockIdx.y * 128;
    const int bn = blockIdx.x * 128;
    const int wr = (wave >> 1) * 64;
    const int wc = (wave & 1) * 64;

    const int srow = lane >> 2;
    const int scol = (lane & 3) * 8;
    const _Float16* gA0 = Ae + (size_t)(bm + wave * 32 + srow) * KEXT + scol;
    const _Float16* gA1 = gA0 + (size_t)16 * KEXT;
    const _Float16* gB0 = Be + (size_t)(bn + wave * 32 + srow) * KEXT + scol;
    const _Float16* gB1 = gB0 + (size_t)16 * KEXT;
    _Float16* lA0 = &As[(wave * 32) * 32];
    _Float16* lA1 = &As[(wave * 32 + 16) * 32];
    _Float16* lB0 = &Bs[(wave * 32) * 32];
    _Float16* lB1 = &Bs[(wave * 32 + 16) * 32];

    const int fm = lane & 15;
    const int fq = (lane >> 4) * 8;

    f32x4 acc[4][4] = {};

    for (int k0 = 0; k0 < KEXT; k0 += 32) {
        load_lds16(gA0 + k0, lA0);
        load_lds16(gA1 + k0, lA1);
        load_lds16(gB0 + k0, lB0);
        load_lds16(gB1 + k0, lB1);
        __syncthreads();

        f16x8 a[4], b[4];
        #pragma unroll
        for (int mt = 0; mt < 4; ++mt)
            a[mt] = *(const f16x8*)&As[(wr + mt * 16 + fm) * 32 + fq];
        #pragma unroll
        for (int nt = 0; nt < 4; ++nt)
            b[nt] = *(const f16x8*)&Bs[(wc + nt * 16 + fm) * 32 + fq];
        #pragma unroll
        for (int mt = 0; mt < 4; ++mt)
            #pragma unroll
            for (int nt = 0; nt < 4; ++nt)
                acc[mt][nt] = __builtin_amdgcn_mfma_f32_16x16x32_f16(
                    a[mt], b[nt], acc[mt][nt], 0, 0, 0);
        __syncthreads();
    }

    const int rquad = (lane >> 4) * 4;
    #pragma unroll
    for (int mt = 0; mt < 4; ++mt) {
        #pragma unroll
        for (int nt = 0; nt < 4; ++nt) {
            const int col = bn + wc + nt * 16 + fm;
            #pragma unroll
            for (int i = 0; i < 4; ++i) {
                const int row = bm + wr + mt * 16 + rquad + i;
                float val = acc[mt][nt][i];
                if (mode == 0) {
                    val *= (1.0f / 1024.0f);
                    if (col < 1024)
                        qkv[(size_t)row * 3072 + col] = val + bq[col];
                    else if (col < 2048)
                        qkv[(size_t)row * 3072 + col] = val + bk[col - 1024];
                    else if (col < 3072)
                        qkv[(size_t)row * 3072 + col] = val + bv[col - 2048];
                    else {
                        const int c = col - 3072;
                        if (c < 16)
                            ab[(size_t)row * 32 + c] = 1.f / (1.f + expf(-val));
                        else if (c < 32)
                            ab[(size_t)row * 32 + c] =
                                fmaxf(val, 0.f) + log1pf(expf(-fabsf(val)));
                    }
                } else {
                    outp[(size_t)row * 1024 + col] = val * 64.f + bo[col];
                }
            }
        }
    }
}

// ---------------------------------------------------------------------------
// DPP 16-lane reduction (xor1, xor2, row_ror:4, row_ror:8 -> all lanes hold sum)
// ---------------------------------------------------------------------------
template <int CTRL>
__device__ __forceinline__ float dpp_addf(float x) {
    int y = __builtin_amdgcn_update_dpp(0, __builtin_bit_cast(int, x),
                                        CTRL, 0xF, 0xF, true);
    return x + __builtin_bit_cast(float, y);
}
__device__ __forceinline__ float red16(float x) {
    x = dpp_addf<0xB1>(x);
    x = dpp_addf<0x4E>(x);
    x = dpp_addf<0x124>(x);
    x = dpp_addf<0x128>(x);
    return x;
}

// ---------------------------------------------------------------------------
// Gated delta recurrence, row-split. 512 blocks x 64 threads.
// blk -> chain bh = blk%32 (all 16 slices of a chain share blk%8 -> same XCD
// -> shared L2 for k/q re-reads), slice s = blk/32 (4 state rows).
// k/q staged via global_load_lds (async, no reg round-trip), v/alpha/beta via
// tiny reg prefetch. Output att in TRANSPOSED layout [B][NH][D][L]: o
// accumulated 4 steps -> one float4 store per row per 4 steps (coalesced).
// ---------------------------------------------------------------------------
__global__ __launch_bounds__(64) void gdn_recurrence(
    const float* __restrict__ qkv, const float* __restrict__ ab,
    float* __restrict__ att)
{
    __shared__ __align__(16) float ks[2][RCT][64];
    __shared__ __align__(16) float qs[2][RCT][64];
    __shared__ __align__(16) float vs_[2][RCT][4];
    __shared__ float gab[2][64];

    const int blk = blockIdx.x;
    const int bh = blk & 31;          // chain (XCD co-location)
    const int s  = blk >> 5;          // row-slice 0..15
    const int b  = bh >> 4;
    const int h  = bh & 15;
    const int lane = threadIdx.x;
    const int rl = lane >> 4;         // local row 0..3
    const int el = lane & 15;         // e-slice
    const int e0 = el * 4;
    const int r0 = s * 4;

    const float* qb  = qkv + (size_t)b * LL * 3072 + h * 64;
    const float* kb  = qb + 1024;
    const float* vb  = qb + 2048 + r0;
    const float* abp = ab + (size_t)b * LL * 32 + h;
    float* op = att + ((size_t)(b * NH + h) * DD + r0 + rl) * LL;

    // per-lane gather offsets for k/q staging: lane covers (t-within-4, d)
    const int st = lane >> 4;          // 0..3
    const int sd = (lane & 15) * 4;    // d offset

    float S0 = 0.f, S1 = 0.f, S2 = 0.f, S3 = 0.f;

    // ---- async-stage k/q chunk 0, reg-load v/ab chunk 0 ----
    {
        const size_t ro = (size_t)st * 3072 + sd;
        #pragma unroll
        for (int m = 0; m < 8; ++m) {
            load_lds16(kb + ro + (size_t)m * 4 * 3072, &ks[0][m * 4][0]);
            load_lds16(qb + ro + (size_t)m * 4 * 3072, &qs[0][m * 4][0]);
        }
        float4 pv = make_float4(0.f,0.f,0.f,0.f);
        if (lane < RCT) pv = *(const float4*)(vb + (size_t)lane * 3072);
        float pab = (lane < 32) ? abp[(size_t)lane * 32]
                                : abp[(size_t)(lane - 32) * 32 + 16];
        if (lane < RCT) *(float4*)&vs_[0][lane][0] = pv;
        gab[0][lane] = pab;
    }
    __syncthreads();

    const int NCHUNK = LL / RCT;
    for (int c = 0; c < NCHUNK; ++c) {
        const int cur = c & 1, nxt = cur ^ 1;
        const bool more = (c + 1 < NCHUNK);

        // issue async staging for chunk c+1; tiny reg prefetch for v/ab
        float4 pv = make_float4(0.f,0.f,0.f,0.f);
        float pab = 0.f;
        if (more) {
            const size_t t0 = (size_t)(c + 1) * RCT;
            const size_t ro = (t0 + st) * 3072 + sd;
            #pragma unroll
            for (int m = 0; m < 8; ++m) {
                load_lds16(kb + ro + (size_t)m * 4 * 3072, &ks[nxt][m * 4][0]);
                load_lds16(qb + ro + (size_t)m * 4 * 3072, &qs[nxt][m * 4][0]);
            }
            if (lane < RCT) pv = *(const float4*)(vb + (t0 + lane) * 3072);
            pab = (lane < 32) ? abp[(t0 + lane) * 32]
                              : abp[(t0 + lane - 32) * 32 + 16];
        }

        // ---- 32 steps from buffer cur, 1-step LDS->reg prefetch ----
        float4 kc = *(const float4*)&ks[cur][0][e0];
        float4 qc = *(const float4*)&qs[cur][0][e0];
        float vc = vs_[cur][0][rl];
        float ac = gab[cur][0];
        float bc = gab[cur][32];

        float o0 = 0.f, o1 = 0.f, o2 = 0.f;
        #pragma unroll 4
        for (int t = 0; t < RCT; ++t) {
            const int tn = (t + 1) & (RCT - 1);
            float4 kn = *(const float4*)&ks[cur][tn][e0];
            float4 qn = *(const float4*)&qs[cur][tn][e0];
            const float vn  = vs_[cur][tn][rl];
            const float an  = gab[cur][tn];
            const float bn2 = gab[cur][32 + tn];

            // sk = (S . k) row-dot
            float p0 = fmaf(S1, kc.y, S0 * kc.x);
            float p1 = fmaf(S3, kc.w, S2 * kc.z);
            float sk = red16(p0 + p1);

            const float cf = bc * fmaf(-ac, sk, vc);

            S0 = fmaf(ac, S0, cf * kc.x);
            S1 = fmaf(ac, S1, cf * kc.y);
            S2 = fmaf(ac, S2, cf * kc.z);
            S3 = fmaf(ac, S3, cf * kc.w);

            float q0 = fmaf(S1, qc.y, S0 * qc.x);
            float q1 = fmaf(S3, qc.w, S2 * qc.z);
            float o = red16(q0 + q1);

            const int ph = t & 3;
            if (ph == 0) o0 = o;
            else if (ph == 1) o1 = o;
            else if (ph == 2) o2 = o;
            else if (el == 0)
                *(float4*)(op + c * RCT + t - 3) = make_float4(o0, o1, o2, o);

            kc = kn; qc = qn; vc = vn; ac = an; bc = bn2;
        }

        // commit v/ab prefetch into next buffer, then publish
        if (more) {
            if (lane < RCT) *(float4*)&vs_[nxt][lane][0] = pv;
            gab[nxt][lane] = pab;
        }
        __syncthreads();
    }
}

// ---------------------------------------------------------------------------
// Fused: residual depthwise causal conv (on the bug-compat reshaped view)
// + transpose back + split-f16 convert for the out-projection A matrix.
// Input att[b][h][d][l] (transposed). View row i = h*64 + l/16,
// col c = (l%16)*64 + d; taps at view rows i-1..i-3 => l - 16*(3-j),
// borrowing from plane h-1 when l goes negative; zero when h==0.
// Output Ae[row = b*1024 + i][KEXT hi|lo|hi] with scale 2^-12.
// ---------------------------------------------------------------------------
__global__ __launch_bounds__(256) void conv_convert(
    const float* __restrict__ att, const float* __restrict__ Wconv,
    _Float16* __restrict__ Ae)
{
    __shared__ float yt[112][68];   // [48-halo + 64 l][d]
    const int lb = blockIdx.x;      // l-block 0..15
    const int h  = blockIdx.y;      // 0..15
    const int b  = blockIdx.z;      // 0..1
    const int tid = threadIdx.x;

    // stage: thread (d = tid>>2, part = tid&3) loads 7 float4 along l
    {
        const int d = tid >> 2;
        const int part = tid & 3;
        const float* src  = att + ((size_t)(b * NH + h) * DD + d) * LL;
        const float* srcm = src - (size_t)DD * LL;  // h-1 plane
        #pragma unroll
        for (int m = 0; m < 7; ++m) {
            const int off = (part * 7 + m) * 4;      // 0,4,...,108
            const int lg = lb * 64 - 48 + off;
            float4 v;
            if (lg >= 0)      v = *(const float4*)(src + lg);
            else if (h > 0)   v = *(const float4*)(srcm + lg + 1024);
            else              v = make_float4(0.f, 0.f, 0.f, 0.f);
            yt[off + 0][d] = v.x; yt[off + 1][d] = v.y;
            yt[off + 2][d] = v.z; yt[off + 3][d] = v.w;
        }
    }
    __syncthreads();

    // thread covers cols c = tid*4 .. tid*4+3 of 4 consecutive Ae rows:
    // c/64 = tid>>4 = l%16 (fixed), d = (tid&15)*4 + k (consecutive)
    float4 w[4];
    #pragma unroll
    for (int k = 0; k < 4; ++k)
        w[k] = ((const float4*)Wconv)[tid * 4 + k];

    const int d0 = (tid & 15) * 4;
    const int lq = tid >> 4;
    const float sc = 1.f / 4096.f;

    #pragma unroll
    for (int rr = 0; rr < 4; ++rr) {
        const int ll = rr * 16 + lq;     // l within block's 64
        float y0[4], y1[4], y2[4], y3[4];
        *(float4*)y0 = *(const float4*)&yt[ll +  0][d0];
        *(float4*)y1 = *(const float4*)&yt[ll + 16][d0];
        *(float4*)y2 = *(const float4*)&yt[ll + 32][d0];
        *(float4*)y3 = *(const float4*)&yt[ll + 48][d0];
        f16x4 hi, lo;
        #pragma unroll
        for (int k = 0; k < 4; ++k) {
            float acc = y3[k];
            acc = fmaf(w[k].x, y0[k], acc);
            acc = fmaf(w[k].y, y1[k], acc);
            acc = fmaf(w[k].z, y2[k], acc);
            acc = fmaf(w[k].w, y3[k], acc);
            acc *= sc;
            hi[k] = (_Float16)acc;
            lo[k] = (_Float16)(acc - (float)hi[k]);
        }
        const size_t row = (size_t)b * 1024 + h * 64 + lb * 4 + rr;
        _Float16* base = Ae + row * KEXT + tid * 4;
        *(f16x4*)(base)        = hi;
        *(f16x4*)(base + 1024) = lo;
        *(f16x4*)(base + 2048) = hi;
    }
}

// ---------------------------------------------------------------------------
extern "C" void kernel_launch(void* const* d_in, const int* in_sizes, int n_in,
                              void* d_out, int out_size, void* d_ws, size_t ws_size,
                              hipStream_t stream)
{
    const float* hs    = (const float*)d_in[0];
    const float* Wq    = (const float*)d_in[1];
    const float* bq    = (const float*)d_in[2];
    const float* Wk    = (const float*)d_in[3];
    const float* bk    = (const float*)d_in[4];
    const float* Wv    = (const float*)d_in[5];
    const float* bv    = (const float*)d_in[6];
    const float* Wa    = (const float*)d_in[7];
    const float* Wb    = (const float*)d_in[8];
    const float* Wconv = (const float*)d_in[9];
    const float* Wo    = (const float*)d_in[10];
    const float* bo    = (const float*)d_in[11];
    float* out = (float*)d_out;

    // workspace layout
    char* w = (char*)d_ws;
    float* qkv = (float*)w;        w += (size_t)MM * 3072 * 4;     // 25.2 MB
    float* att = (float*)w;        w += (size_t)MM * 1024 * 4;     //  8.4 MB (transposed [B][NH][D][L])
    float* ab  = (float*)w;        w += (size_t)MM * 32 * 4;       //  0.26 MB
    _Float16* Ae = (_Float16*)w;   w += (size_t)MM * KEXT * 2;     // 12.6 MB
    _Float16* Be = (_Float16*)w;   w += (size_t)NB_QKV * KEXT * 2; // 19.7 MB

    // 1) split-f16 conversions for the fused qkv/alpha/beta GEMM
    hipLaunchKernelGGL(convert_A, dim3(MM), dim3(256), 0, stream, hs, Ae, 16.f);
    hipLaunchKernelGGL(convert_Wqkv, dim3(NB_QKV), dim3(256), 0, stream,
                       Wq, Wk, Wv, Wa, Wb, Be);

    // 2) fused q/k/v/alpha/beta projection via f16-split MFMA
    hipLaunchKernelGGL(mfma_gemm, dim3(NB_QKV / 128, MM / 128), dim3(256), 0, stream,
                       Ae, Be, qkv, ab, bq, bk, bv, (float*)nullptr, (const float*)nullptr, 0);

    // 3) gated delta recurrence (512 one-wave blocks, XCD-co-located slices)
    hipLaunchKernelGGL(gdn_recurrence, dim3(512), dim3(64), 0, stream, qkv, ab, att);

    // 4) fused conv + transpose + split-f16 convert (writes Ae for out-proj)
    hipLaunchKernelGGL(conv_convert, dim3(16, 16, BB), dim3(256), 0, stream,
                       att, Wconv, Ae);

    // 5) out-projection
    hipLaunchKernelGGL(convert_Wo, dim3(1024), dim3(256), 0, stream, Wo, Be);
    hipLaunchKernelGGL(mfma_gemm, dim3(1024 / 128, MM / 128), dim3(256), 0, stream,
                       Ae, Be, (float*)nullptr, (float*)nullptr,
                       (const float*)nullptr, (const float*)nullptr, (const float*)nullptr,
                       out, bo, 1);
}